// Round 9
// baseline (344.761 us; speedup 1.0000x reference)
//
#include <hip/hip_runtime.h>
#include <stdint.h>

typedef __attribute__((ext_vector_type(4))) int int4v;

#define K_IN 4096
#define N_OUT 4096
#define NKT 64             // K-tiles of 128 i8 elems (32 hi + 32 lo)

// W_i8[o][k] = (int8)(q[o][k] - zp[o])  (exact, in [-10,9])
__global__ void prep_w_kernel(const int* __restrict__ q, const float* __restrict__ zp,
                              signed char* __restrict__ W) {
  size_t t = (size_t)blockIdx.x * blockDim.x + threadIdx.x;
  size_t base = t * 8;
  int o = (int)(base >> 12);
  int z = (int)zp[o];                        // zp is an integral float
  int4 q0 = *(const int4*)(q + base);
  int4 q1 = *(const int4*)(q + base + 4);
  int v[8] = {q0.x, q0.y, q0.z, q0.w, q1.x, q1.y, q1.z, q1.w};
  union { signed char c[8]; uint64_t u; } pk;
#pragma unroll
  for (int j = 0; j < 8; ++j) pk.c[j] = (signed char)(v[j] - z);
  *(uint64_t*)(W + (size_t)o * K_IN + (base & 4095)) = pk.u;
}

// X14 = clamp(round(x*1024), +-8191) = 128*hi + lo; A[m][k]=hi, A[m][4096+k]=lo
__global__ void prep_a_kernel(const float* __restrict__ x, signed char* __restrict__ A) {
  size_t t = (size_t)blockIdx.x * blockDim.x + threadIdx.x;
  size_t base = t * 8;
  size_t m = base >> 12;
  int k = (int)(base & 4095);
  float4 x0 = *(const float4*)(x + base);
  float4 x1 = *(const float4*)(x + base + 4);
  float xs[8] = {x0.x, x0.y, x0.z, x0.w, x1.x, x1.y, x1.z, x1.w};
  union { signed char c[8]; uint64_t u; } hp, lp;
#pragma unroll
  for (int j = 0; j < 8; ++j) {
    int X = __float2int_rn(xs[j] * 1024.0f);
    X = X > 8191 ? 8191 : (X < -8191 ? -8191 : X);
    int hi = (X + 64) >> 7;                  // in [-64,64]
    int lo = X - (hi << 7);                  // in [-64,63]
    hp.c[j] = (signed char)hi;
    lp.c[j] = (signed char)lo;
  }
  size_t row = m * (size_t)(2 * K_IN);
  *(uint64_t*)(A + row + k) = hp.u;
  *(uint64_t*)(A + row + K_IN + k) = lp.u;
}

// ---------------------------------------------------------------------------
// 256x256 i8 GEMM, A-only LDS (64 KiB dbuf), B direct global->VGPR ping-pong.
// Per K-tile (BK=128): 4 phases, ONE barrier (at p1), uniform vmcnt(8) at p1.
// Issue order per kt: p1: 8 B-loads(kt+1); p2/p3: 4 A-stages(kt+1)->other buf.
// p1's vmcnt(8) drains exactly B(kt)+A(kt) (pending 20 -> 8); barrier then
// makes A(kt) collectively visible. Stage-WAR: that buffer's reads were
// drained by LGKM0s program-order before the p1 barrier.
// Swizzle (A only): 16B-chunk c of row r holds global chunk c ^ (r&7).
// ---------------------------------------------------------------------------
#define A0OFF 0
#define A1OFF 32768

#define STAGE_A(kt, u, bufOff)                                                   \
  __builtin_amdgcn_global_load_lds(                                              \
      (const __attribute__((address_space(1))) void*)(Ag +                       \
          (size_t)(u) * 64 * (2 * K_IN) + (size_t)((kt) & (NKT - 1)) * 128 +     \
          laneOffA),                                                             \
      (__attribute__((address_space(3))) void*)(lds + (bufOff) + (u) * 8192 +    \
          wid * 1024), 16, 0, 0);

#define READ_A(dst, bufOff, q)                                                   \
  _Pragma("unroll") for (int m2 = 0; m2 < 2; ++m2)                               \
    _Pragma("unroll") for (int kc = 0; kc < 2; ++kc)                             \
      dst[m2][kc] = *(const int4v*)&lds[(bufOff) +                               \
          (wmBase + ((q) * 2 + m2) * 16 + fr) * 128 + ((kc * 64 + fk16) ^ fswz)];

#define LOAD_B(dst, kt)                                                          \
  _Pragma("unroll") for (int n = 0; n < 4; ++n)                                  \
    _Pragma("unroll") for (int kc = 0; kc < 2; ++kc)                             \
      dst[n][kc] = *(const int4v*)(Bl + (size_t)(n * 16) * K_IN +                \
          (size_t)((kt) & 31) * 128 + kc * 64);

#define LGKM0 asm volatile("s_waitcnt lgkmcnt(0)" ::: "memory");                 \
  __builtin_amdgcn_sched_barrier(0);
#define VM8 asm volatile("s_waitcnt vmcnt(8)" ::: "memory");                     \
  __builtin_amdgcn_sched_barrier(0);
#define BAR __builtin_amdgcn_s_barrier();

#define MFMA16(src, BF, q)                                                       \
  __builtin_amdgcn_s_setprio(1);                                                 \
  _Pragma("unroll") for (int kc = 0; kc < 2; ++kc)                               \
    _Pragma("unroll") for (int m2 = 0; m2 < 2; ++m2)                             \
      _Pragma("unroll") for (int n = 0; n < 4; ++n)                              \
        acc[(q) * 2 + m2][n] = __builtin_amdgcn_mfma_i32_16x16x64_i8(            \
            src[m2][kc], BF[n][kc], acc[(q) * 2 + m2][n], 0, 0, 0);              \
  __builtin_amdgcn_s_setprio(0);

// one K-tile: read A from bufR, use BFu regs; prefetch B(kt+1)->BFl,
// stage A(kt+1)->bufW.
#define KTILE(bufR, bufW, BFu, BFl, kt)                                          \
  {                                                                              \
    /* p1 */                                                                     \
    LOAD_B(BFl, (kt) + 1)                                                        \
    VM8 BAR                                                                      \
    READ_A(aS, bufR, 0)                                                          \
    LGKM0 MFMA16(aS, BFu, 0) READ_A(aT, bufR, 1)                                 \
    /* p2 */                                                                     \
    STAGE_A((kt) + 1, 0, bufW) STAGE_A((kt) + 1, 1, bufW)                        \
    LGKM0 MFMA16(aT, BFu, 1) READ_A(aS, bufR, 2)                                 \
    /* p3 */                                                                     \
    STAGE_A((kt) + 1, 2, bufW) STAGE_A((kt) + 1, 3, bufW)                        \
    LGKM0 MFMA16(aS, BFu, 2) READ_A(aT, bufR, 3)                                 \
    /* p4 */                                                                     \
    LGKM0 MFMA16(aT, BFu, 3)                                                     \
  }

__global__ __launch_bounds__(512, 2) void gemm_kernel(
    const signed char* __restrict__ A, const signed char* __restrict__ B,
    const float* __restrict__ scale, float* __restrict__ C) {
  __shared__ unsigned char lds[65536];      // 64 KiB, A only

  const int tid = threadIdx.x;
  const int lane = tid & 63;
  const int wid = tid >> 6;                 // 0..7
  const int wmBase = (wid >> 2) * 128;      // wave M offset in tile
  const int wnBase = (wid & 3) * 64;        // wave N offset in tile

  // XCD-aware bijective swizzle: 512 blocks, 512 % 8 == 0
  const int bid = blockIdx.x;
  const int swz = (bid & 7) * 64 + (bid >> 3);
  const int tn = swz & 15;                  // 16 N-tiles
  const int tm = swz >> 4;                  // 32 M-tiles

  const signed char* Ag = A + (size_t)tm * 256 * (2 * K_IN);

  // per-lane A staging source: row-in-unit = wid*8 + lane/8,
  // global 16B-chunk = (lane&7) ^ (lane>>3)  (inverse swizzle)
  const size_t laneOffA =
      (size_t)(wid * 8 + (lane >> 3)) * (2 * K_IN) + 16 * ((lane & 7) ^ (lane >> 3));

  // fragment addressing (byte units)
  const int fr = lane & 15;
  const int fk16 = (lane >> 4) * 16;
  const int fswz = (fr & 7) * 16;

  // per-lane B fragment base: row = tn*256 + wnBase + fr, k-byte fk16
  const signed char* Bl =
      B + (size_t)(tn * 256 + wnBase + fr) * K_IN + fk16;

  int4v acc[8][4];
#pragma unroll
  for (int i = 0; i < 8; ++i)
#pragma unroll
    for (int j = 0; j < 4; ++j) acc[i][j] = (int4v){0, 0, 0, 0};
  int4v bfP[4][2], bfQ[4][2];               // B ping-pong (even/odd kt)
  int4v aS[2][2], aT[2][2];                 // A fragment ping-pong

  // ---- prologue: A(0) 4 stages + B(0) 8 loads = 12 pending
  STAGE_A(0, 0, A0OFF) STAGE_A(0, 1, A0OFF)
  STAGE_A(0, 2, A0OFF) STAGE_A(0, 3, A0OFF)
  LOAD_B(bfP, 0)

  // hi slice: K-tiles 0..31
  for (int t = 0; t < 16; ++t) {
    KTILE(A0OFF, A1OFF, bfP, bfQ, 2 * t)
    KTILE(A1OFF, A0OFF, bfQ, bfP, 2 * t + 1)
  }

  // exact mid-point scaling: total = 128*hi_sum + lo_sum
#pragma unroll
  for (int i = 0; i < 8; ++i)
#pragma unroll
    for (int j = 0; j < 4; ++j) acc[i][j] <<= 7;

  // lo slice: K-tiles 32..63
  for (int t = 16; t < 32; ++t) {
    KTILE(A0OFF, A1OFF, bfP, bfQ, 2 * t)
    KTILE(A1OFF, A0OFF, bfQ, bfP, 2 * t + 1)
  }

  // epilogue: row = (lane>>4)*4 + r (+m*16), col = lane&15 (+n*16)
  const int r0 = tm * 256 + wmBase + ((lane >> 4) << 2);
  const int c0 = tn * 256 + wnBase + (lane & 15);
#pragma unroll
  for (int n = 0; n < 4; ++n) {
    float s = scale[c0 + n * 16] * (1.0f / 1024.0f);
#pragma unroll
    for (int m = 0; m < 8; ++m)
#pragma unroll
      for (int r = 0; r < 4; ++r)
        C[(size_t)(r0 + m * 16 + r) * N_OUT + c0 + n * 16] = (float)acc[m][n][r] * s;
  }
}

// correctness safety net if ws_size is too small for the staged path
__global__ void fallback_kernel(const float* __restrict__ x, const float* __restrict__ scale,
                                const float* __restrict__ zp, const int* __restrict__ q,
                                float* __restrict__ y) {
  int o = blockIdx.x * blockDim.x + threadIdx.x;
  int m = blockIdx.y;
  float z = zp[o];
  const int* qr = q + (size_t)o * K_IN;
  const float* xr = x + (size_t)m * K_IN;
  float acc = 0.f;
  for (int k = 0; k < K_IN; k += 4) {
    int4 qq = *(const int4*)(qr + k);
    float4 xx = *(const float4*)(xr + k);
    acc += xx.x * ((float)qq.x - z) + xx.y * ((float)qq.y - z)
         + xx.z * ((float)qq.z - z) + xx.w * ((float)qq.w - z);
  }
  y[(size_t)m * N_OUT + o] = acc * scale[o];
}

extern "C" void kernel_launch(void* const* d_in, const int* in_sizes, int n_in,
                              void* d_out, int out_size, void* d_ws, size_t ws_size,
                              hipStream_t stream) {
  const float* x     = (const float*)d_in[0];
  const float* scale = (const float*)d_in[1];
  const float* zp    = (const float*)d_in[2];
  const int*   q     = (const int*)d_in[3];
  float* y = (float*)d_out;
  const int M = in_sizes[0] / K_IN;          // 8192

  size_t wbytes = (size_t)N_OUT * K_IN;      // 16 MiB
  size_t abytes = (size_t)M * 2 * K_IN;      // 64 MiB
  if (ws_size >= wbytes + abytes && (M % 256) == 0) {
    signed char* W = (signed char*)d_ws;
    signed char* Abuf = W + wbytes;
    unsigned gw = (unsigned)(((size_t)N_OUT * K_IN) / (8 * 256));
    unsigned ga = (unsigned)(((size_t)M * K_IN) / (8 * 256));
    prep_w_kernel<<<gw, 256, 0, stream>>>(q, zp, W);
    prep_a_kernel<<<ga, 256, 0, stream>>>(x, Abuf);
    unsigned nblocks = (unsigned)((M / 256) * (N_OUT / 256));  // 512
    gemm_kernel<<<nblocks, 512, 0, stream>>>(Abuf, W, scale, y);
  } else {
    dim3 grid(N_OUT / 256, M);
    fallback_kernel<<<grid, 256, 0, stream>>>(x, scale, zp, q, y);
  }
}

// Round 10
// 279.032 us; speedup vs baseline: 1.2356x; 1.2356x over previous
//
#include <hip/hip_runtime.h>
#include <stdint.h>

typedef __attribute__((ext_vector_type(4))) int int4v;

#define K_IN 4096
#define N_OUT 4096
#define NKT 64             // K-tiles of 128 i8 elems (32 hi + 32 lo)

// W_i8[o][k] = (int8)(q[o][k] - zp[o])  (exact, in [-10,9])
__global__ void prep_w_kernel(const int* __restrict__ q, const float* __restrict__ zp,
                              signed char* __restrict__ W) {
  size_t t = (size_t)blockIdx.x * blockDim.x + threadIdx.x;
  size_t base = t * 8;
  int o = (int)(base >> 12);
  int z = (int)zp[o];                        // zp is an integral float
  int4 q0 = *(const int4*)(q + base);
  int4 q1 = *(const int4*)(q + base + 4);
  int v[8] = {q0.x, q0.y, q0.z, q0.w, q1.x, q1.y, q1.z, q1.w};
  union { signed char c[8]; uint64_t u; } pk;
#pragma unroll
  for (int j = 0; j < 8; ++j) pk.c[j] = (signed char)(v[j] - z);
  *(uint64_t*)(W + (size_t)o * K_IN + (base & 4095)) = pk.u;
}

// X14 = clamp(round(x*1024), +-8191) = 128*hi + lo; A[m][k]=hi, A[m][4096+k]=lo
__global__ void prep_a_kernel(const float* __restrict__ x, signed char* __restrict__ A) {
  size_t t = (size_t)blockIdx.x * blockDim.x + threadIdx.x;
  size_t base = t * 8;
  size_t m = base >> 12;
  int k = (int)(base & 4095);
  float4 x0 = *(const float4*)(x + base);
  float4 x1 = *(const float4*)(x + base + 4);
  float xs[8] = {x0.x, x0.y, x0.z, x0.w, x1.x, x1.y, x1.z, x1.w};
  union { signed char c[8]; uint64_t u; } hp, lp;
#pragma unroll
  for (int j = 0; j < 8; ++j) {
    int X = __float2int_rn(xs[j] * 1024.0f);
    X = X > 8191 ? 8191 : (X < -8191 ? -8191 : X);
    int hi = (X + 64) >> 7;                  // in [-64,64]
    int lo = X - (hi << 7);                  // in [-64,63]
    hp.c[j] = (signed char)hi;
    lp.c[j] = (signed char)lo;
  }
  size_t row = m * (size_t)(2 * K_IN);
  *(uint64_t*)(A + row + k) = hp.u;
  *(uint64_t*)(A + row + K_IN + k) = lp.u;
}

// ---------------------------------------------------------------------------
// 256x256 i8 GEMM, clean full double-buffer (A and B), ONE barrier + ONE
// vmcnt(0) per K-tile. Per K-tile kt (read buf R=kt&1, write W=(kt+1)&1):
//   vmcnt(0)   - drains this wave's stages of kt (issued a full K-tile ago)
//   s_barrier  - all waves drained => R complete & visible; all reads of W
//                from kt-1 were consumed before each wave's barrier arrival
//   STAGE(kt+1)->W  (WAR-safe after barrier)
//   plain ds_reads + MFMA  (compiler inserts fine-grained lgkmcnt - m97)
// Swizzle: 16B-chunk c of row r holds global chunk c ^ (r&7); linear LDS
// dest, inverse-swizzled global source (rule #21).
// ---------------------------------------------------------------------------
#define A0OFF 0
#define A1OFF 32768
#define B0OFF 65536
#define B1OFF 98304

#define STAGE_A(kt, u, ldsOff)                                                   \
  __builtin_amdgcn_global_load_lds(                                              \
      (const __attribute__((address_space(1))) void*)(Ag +                       \
          (size_t)(u) * 64 * (2 * K_IN) + (size_t)((kt) & (NKT - 1)) * 128 +     \
          laneOffA),                                                             \
      (__attribute__((address_space(3))) void*)(lds + (ldsOff) + (u) * 8192 +    \
          wid * 1024), 16, 0, 0);

#define STAGE_B(kt, u, ldsOff)                                                   \
  __builtin_amdgcn_global_load_lds(                                              \
      (const __attribute__((address_space(1))) void*)(Bg +                       \
          (size_t)(u) * 64 * K_IN + (size_t)((kt) & 31) * 128 + laneOffB),       \
      (__attribute__((address_space(3))) void*)(lds + (ldsOff) + (u) * 8192 +    \
          wid * 1024), 16, 0, 0);

#define READ_A(dst, bufOff, q)                                                   \
  _Pragma("unroll") for (int m2 = 0; m2 < 2; ++m2)                               \
    _Pragma("unroll") for (int kc = 0; kc < 2; ++kc)                             \
      dst[m2][kc] = *(const int4v*)&lds[(bufOff) +                               \
          (wmBase + ((q) * 2 + m2) * 16 + fr) * 128 + ((kc * 64 + fk16) ^ fswz)];

#define READ_B(bufOff)                                                           \
  _Pragma("unroll") for (int n = 0; n < 4; ++n)                                  \
    _Pragma("unroll") for (int kc = 0; kc < 2; ++kc)                             \
      bf[n][kc] = *(const int4v*)&lds[(bufOff) +                                 \
          (wnBase + n * 16 + fr) * 128 + ((kc * 64 + fk16) ^ fswz)];

#define MFMA8(src, q)                                                            \
  __builtin_amdgcn_s_setprio(1);                                                 \
  _Pragma("unroll") for (int kc = 0; kc < 2; ++kc)                               \
    _Pragma("unroll") for (int m2 = 0; m2 < 2; ++m2)                             \
      _Pragma("unroll") for (int n = 0; n < 4; ++n)                              \
        acc[(q) * 2 + m2][n] = __builtin_amdgcn_mfma_i32_16x16x64_i8(            \
            src[m2][kc], bf[n][kc], acc[(q) * 2 + m2][n], 0, 0, 0);              \
  __builtin_amdgcn_s_setprio(0);

// one K-tile: sync, stage kt+1 into W, compute from R
#define KTILE(RA, RB, WA, WB, kt)                                                \
  {                                                                              \
    asm volatile("s_waitcnt vmcnt(0)" ::: "memory");                             \
    __builtin_amdgcn_sched_barrier(0);                                           \
    __builtin_amdgcn_s_barrier();                                                \
    __builtin_amdgcn_sched_barrier(0);                                           \
    STAGE_A((kt) + 1, 0, WA) STAGE_A((kt) + 1, 1, WA)                            \
    STAGE_A((kt) + 1, 2, WA) STAGE_A((kt) + 1, 3, WA)                            \
    STAGE_B((kt) + 1, 0, WB) STAGE_B((kt) + 1, 1, WB)                            \
    STAGE_B((kt) + 1, 2, WB) STAGE_B((kt) + 1, 3, WB)                            \
    READ_B(RB)                                                                   \
    READ_A(aS, RA, 0)                                                            \
    MFMA8(aS, 0) READ_A(aT, RA, 1)                                               \
    MFMA8(aT, 1) READ_A(aS, RA, 2)                                               \
    MFMA8(aS, 2) READ_A(aT, RA, 3)                                               \
    MFMA8(aT, 3)                                                                 \
  }

__global__ __launch_bounds__(512, 2) void gemm_kernel(
    const signed char* __restrict__ A, const signed char* __restrict__ B,
    const float* __restrict__ scale, float* __restrict__ C) {
  __shared__ unsigned char lds[131072];     // 128 KiB

  const int tid = threadIdx.x;
  const int lane = tid & 63;
  const int wid = tid >> 6;                 // 0..7
  const int wmBase = (wid >> 2) * 128;      // wave M offset in tile
  const int wnBase = (wid & 3) * 64;        // wave N offset in tile

  // XCD-aware bijective swizzle: 512 blocks, 512 % 8 == 0
  const int bid = blockIdx.x;
  const int swz = (bid & 7) * 64 + (bid >> 3);
  const int tn = swz & 15;                  // 16 N-tiles
  const int tm = swz >> 4;                  // 32 M-tiles

  const signed char* Ag = A + (size_t)tm * 256 * (2 * K_IN);
  const signed char* Bg = B + (size_t)tn * 256 * K_IN;

  // per-lane staging source: row-in-unit = wid*8 + lane/8,
  // global 16B-chunk = (lane&7) ^ (lane>>3)  (inverse swizzle)
  const size_t laneOffA =
      (size_t)(wid * 8 + (lane >> 3)) * (2 * K_IN) + 16 * ((lane & 7) ^ (lane >> 3));
  const size_t laneOffB =
      (size_t)(wid * 8 + (lane >> 3)) * K_IN + 16 * ((lane & 7) ^ (lane >> 3));

  // fragment addressing (byte units)
  const int fr = lane & 15;
  const int fk16 = (lane >> 4) * 16;
  const int fswz = (fr & 7) * 16;

  int4v acc[8][4];
#pragma unroll
  for (int i = 0; i < 8; ++i)
#pragma unroll
    for (int j = 0; j < 4; ++j) acc[i][j] = (int4v){0, 0, 0, 0};
  int4v bf[4][2];
  int4v aS[2][2], aT[2][2];

  // ---- prologue: stage K-tile 0 into buffer 0 (8 loads pending)
  STAGE_A(0, 0, A0OFF) STAGE_A(0, 1, A0OFF)
  STAGE_A(0, 2, A0OFF) STAGE_A(0, 3, A0OFF)
  STAGE_B(0, 0, B0OFF) STAGE_B(0, 1, B0OFF)
  STAGE_B(0, 2, B0OFF) STAGE_B(0, 3, B0OFF)

  // hi slice: K-tiles 0..31
  for (int t = 0; t < 16; ++t) {
    KTILE(A0OFF, B0OFF, A1OFF, B1OFF, 2 * t)
    KTILE(A1OFF, B1OFF, A0OFF, B0OFF, 2 * t + 1)
  }

  // exact mid-point scaling: total = 128*hi_sum + lo_sum
#pragma unroll
  for (int i = 0; i < 8; ++i)
#pragma unroll
    for (int j = 0; j < 4; ++j) acc[i][j] <<= 7;

  // lo slice: K-tiles 32..63 (staging continuity: kt=31 staged kt=32)
  for (int t = 16; t < 32; ++t) {
    KTILE(A0OFF, B0OFF, A1OFF, B1OFF, 2 * t)
    KTILE(A1OFF, B1OFF, A0OFF, B0OFF, 2 * t + 1)
  }

  // epilogue: row = (lane>>4)*4 + r (+m*16), col = lane&15 (+n*16)
  const int r0 = tm * 256 + wmBase + ((lane >> 4) << 2);
  const int c0 = tn * 256 + wnBase + (lane & 15);
#pragma unroll
  for (int n = 0; n < 4; ++n) {
    float s = scale[c0 + n * 16] * (1.0f / 1024.0f);
#pragma unroll
    for (int m = 0; m < 8; ++m)
#pragma unroll
      for (int r = 0; r < 4; ++r)
        C[(size_t)(r0 + m * 16 + r) * N_OUT + c0 + n * 16] = (float)acc[m][n][r] * s;
  }
}

// correctness safety net if ws_size is too small for the staged path
__global__ void fallback_kernel(const float* __restrict__ x, const float* __restrict__ scale,
                                const float* __restrict__ zp, const int* __restrict__ q,
                                float* __restrict__ y) {
  int o = blockIdx.x * blockDim.x + threadIdx.x;
  int m = blockIdx.y;
  float z = zp[o];
  const int* qr = q + (size_t)o * K_IN;
  const float* xr = x + (size_t)m * K_IN;
  float acc = 0.f;
  for (int k = 0; k < K_IN; k += 4) {
    int4 qq = *(const int4*)(qr + k);
    float4 xx = *(const float4*)(xr + k);
    acc += xx.x * ((float)qq.x - z) + xx.y * ((float)qq.y - z)
         + xx.z * ((float)qq.z - z) + xx.w * ((float)qq.w - z);
  }
  y[(size_t)m * N_OUT + o] = acc * scale[o];
}

extern "C" void kernel_launch(void* const* d_in, const int* in_sizes, int n_in,
                              void* d_out, int out_size, void* d_ws, size_t ws_size,
                              hipStream_t stream) {
  const float* x     = (const float*)d_in[0];
  const float* scale = (const float*)d_in[1];
  const float* zp    = (const float*)d_in[2];
  const int*   q     = (const int*)d_in[3];
  float* y = (float*)d_out;
  const int M = in_sizes[0] / K_IN;          // 8192

  size_t wbytes = (size_t)N_OUT * K_IN;      // 16 MiB
  size_t abytes = (size_t)M * 2 * K_IN;      // 64 MiB
  if (ws_size >= wbytes + abytes && (M % 256) == 0) {
    signed char* W = (signed char*)d_ws;
    signed char* Abuf = W + wbytes;
    unsigned gw = (unsigned)(((size_t)N_OUT * K_IN) / (8 * 256));
    unsigned ga = (unsigned)(((size_t)M * K_IN) / (8 * 256));
    prep_w_kernel<<<gw, 256, 0, stream>>>(q, zp, W);
    prep_a_kernel<<<ga, 256, 0, stream>>>(x, Abuf);
    unsigned nblocks = (unsigned)((M / 256) * (N_OUT / 256));  // 512
    gemm_kernel<<<nblocks, 512, 0, stream>>>(Abuf, W, scale, y);
  } else {
    dim3 grid(N_OUT / 256, M);
    fallback_kernel<<<grid, 256, 0, stream>>>(x, scale, zp, q, y);
  }
}